// Round 10
// baseline (3676.362 us; speedup 1.0000x reference)
//
#include <hip/hip_runtime.h>

#define Hdim 200
#define NP   800
#define Tlen 100
#define BT   32          // batch rows per WG -> grid = 256 = 1 WG/CU
#define KB   7           // K blocks of 32 (200 -> 224 padded)
#define HS   232         // padded h row stride (ushorts)
#define NT   50          // 800/16 gate-col tiles
#define THREADS 320      // 5 waves x 10 M-tiles each
#define CH   10          // M-tiles per wave
#define CHSTR (NT*64*8)  // ushorts per K-chunk (25600)
#define MATSZ (KB*CHSTR) // 179200 ushorts per packed matrix
#define SBUF  (CH*512)   // ushorts per stage buffer (10 tiles x 512 = 5120)

// s_waitcnt immediates: vm[3:0] in bits3:0, vm[5:4] in bits15:14, lgkm[11:8]
#define WAIT_VM10  0x0F7A   // vmcnt(10): chunk c landed, chunk c+1 (10 DMAs) in flight
#define WAIT_LGKM0 0xC07F   // lgkmcnt(0)

typedef float f32x4 __attribute__((ext_vector_type(4)));
typedef short s16x8 __attribute__((ext_vector_type(8)));

__device__ __forceinline__ ushort f2bf(float f) {
    unsigned u = __float_as_uint(f);
    return (ushort)((u + 0x7fffu + ((u >> 16) & 1u)) >> 16);   // RTNE
}
__device__ __forceinline__ float bf2f(ushort s) {
    return __uint_as_float(((unsigned)s) << 16);
}
__device__ __forceinline__ float sigmoid_fast(float v) {
    return 1.0f / (1.0f + __expf(-v));
}
__device__ __forceinline__ float tanh_fast(float v) {
    return 2.0f / (1.0f + __expf(-2.0f * v)) - 1.0f;
}
// WG barrier WITHOUT vmcnt drain (weight DMAs stay in flight across it).
__device__ __forceinline__ void wg_barrier() {
    asm volatile("" ::: "memory");
    __builtin_amdgcn_s_waitcnt(WAIT_LGKM0);
    __builtin_amdgcn_s_barrier();
    asm volatile("" ::: "memory");
}

// ---- pack 5 recurrent matrices [200][800] fp32 -> bf16 fragment layout ----
// order in d_ws: [U0, W1, U1, W2, U2]
__global__ void pack_weights(const float* __restrict__ U0, const float* __restrict__ W1,
                             const float* __restrict__ U1, const float* __restrict__ W2,
                             const float* __restrict__ U2, ushort* __restrict__ dst) {
    int idx = blockIdx.x * blockDim.x + threadIdx.x;
    if (idx >= 5 * KB * NT * 64) return;
    int lane = idx & 63; int rest = idx >> 6;
    int nt = rest % NT; rest /= NT;
    int kb = rest % KB; int mi = rest / KB;
    const float* src = (mi == 0) ? U0 : (mi == 1) ? W1 : (mi == 2) ? U1 : (mi == 3) ? W2 : U2;
    int np = nt * 16 + (lane & 15);
    int ncol = (np & 3) * Hdim + (np >> 2);          // gate*200 + unit
    int k0 = kb * 32 + (lane >> 4) * 8;
    ushort v[8];
#pragma unroll
    for (int j = 0; j < 8; ++j) {
        int k = k0 + j;
        v[j] = (k < Hdim) ? f2bf(src[k * NP + ncol]) : (ushort)0;
    }
    uint4 o;
    o.x = (unsigned)v[0] | ((unsigned)v[1] << 16);
    o.y = (unsigned)v[2] | ((unsigned)v[3] << 16);
    o.z = (unsigned)v[4] | ((unsigned)v[5] << 16);
    o.w = (unsigned)v[6] | ((unsigned)v[7] << 16);
    ((uint4*)dst)[idx] = o;
}

// 10 async DMAs: one K-chunk's 10 fragment tiles -> wave-private LDS buffer.
__device__ __forceinline__ void stage_chunk(const ushort* gp, ushort* dstbuf, int lane) {
#pragma unroll
    for (int mt = 0; mt < CH; ++mt) {
        __builtin_amdgcn_global_load_lds(
            (const __attribute__((address_space(1))) void*)(gp + (size_t)mt * 512 + lane * 8),
            (__attribute__((address_space(3))) void*)(dstbuf + mt * 512),
            16, 0, 0);
    }
}

__device__ __forceinline__ void unpack4(const ushort* p, float (&o)[4]) {
    uint2 u = *(const uint2*)p;
    o[0] = bf2f((ushort)(u.x));  o[1] = bf2f((ushort)(u.x >> 16));
    o[2] = bf2f((ushort)(u.y));  o[3] = bf2f((ushort)(u.y >> 16));
}

// lane-local cell update: acc[nt][mt] regs r=0..3 = gates i,f,g,o of
// unit u=(ct0+mt)*4+q, batch n=nt*16+l15.
__device__ __forceinline__ void gate_phase(f32x4 (&acc)[2][CH],
                                           float (&creg)[2][CH],
                                           ushort* __restrict__ hbl,
                                           int lane, int ct0) {
    const int l15 = lane & 15, q = lane >> 4;
#pragma unroll
    for (int nt = 0; nt < 2; ++nt) {
#pragma unroll
        for (int mt = 0; mt < CH; ++mt) {
            const int u = (ct0 + mt) * 4 + q;
            const int n = nt * 16 + l15;
            f32x4 z = acc[nt][mt];
            float iv = sigmoid_fast(z[0]);
            float fv = sigmoid_fast(z[1]);
            float gv = tanh_fast(z[2]);
            float ov = sigmoid_fast(z[3]);
            float c = fv * creg[nt][mt] + iv * gv;
            creg[nt][mt] = c;
            hbl[n * HS + u] = f2bf(ov * tanh_fast(c));
        }
    }
}

__global__ void __launch_bounds__(THREADS, 2)
lstm3_mfma(const float* __restrict__ x,
           const float* __restrict__ W0, const float* __restrict__ b0,
           const float* __restrict__ b1, const float* __restrict__ b2,
           const float* __restrict__ Wfc, const float* __restrict__ bfc,
           const ushort* __restrict__ packed,
           float* __restrict__ out) {
    __shared__ ushort hb[3][BT][HS];        // h state, bf16 (44.5 KB)
    __shared__ ushort stage[5][2][SBUF];    // 2-deep wave-private staging (100 KB)
    __shared__ ushort pbwb[4][NP];          // permuted b0,b1,b2,W0 as bf16 (6.4 KB)
    __shared__ ushort xTs[Tlen][BT];        // x transposed, bf16 (6.4 KB)
    __shared__ uint   gTab[35];             // rotated weight-chunk offsets (ushorts)
    __shared__ uint   bhTab[35];            // matching h-operand offsets (ushorts)

    const int tid = threadIdx.x;
    const int wave = tid >> 6, lane = tid & 63;
    const int l15 = lane & 15, q = lane >> 4;
    const int ct0 = wave * CH;
    const int bx = blockIdx.x;
    const int bbase = bx * BT;

    for (int i = tid; i < 3 * BT * HS; i += THREADS) ((ushort*)hb)[i] = 0;
    for (int i = tid; i < NP; i += THREADS) {
        int nc = (i & 3) * Hdim + (i >> 2);   // permuted col -> src col
        pbwb[0][i] = f2bf(b0[nc]); pbwb[1][i] = f2bf(b1[nc]);
        pbwb[2][i] = f2bf(b2[nc]); pbwb[3][i] = f2bf(W0[nc]);
    }
    for (int i = tid; i < BT * Tlen; i += THREADS) {
        int m = i / Tlen, tt = i % Tlen;
        xTs[tt][m] = f2bf(x[(size_t)(bbase + m) * Tlen + tt]);
    }
    // per-WG rotated chunk tables: slot s in [0,35) -> weight offset + h offset
    if (tid < 35) {
        int s = tid; uint goff, bhoff;
        if (s < 7) {                       // layer0: U0, B=h0
            int c = (s + bx) % 7;
            goff = 0u * MATSZ + c * CHSTR;           bhoff = 0u * BT * HS + c * 32;
        } else if (s < 21) {               // layer1: U1 (B=h1) then W1 (B=h0new), rotated
            int c = (s - 7 + bx) % 14;
            if (c < 7) { goff = 2u * MATSZ + c * CHSTR;       bhoff = 1u * BT * HS + c * 32; }
            else       { goff = 1u * MATSZ + (c - 7) * CHSTR; bhoff = 0u * BT * HS + (c - 7) * 32; }
        } else {                           // layer2: U2 (B=h2) then W2 (B=h1new), rotated
            int c = (s - 21 + bx * 5) % 14;
            if (c < 7) { goff = 4u * MATSZ + c * CHSTR;       bhoff = 2u * BT * HS + c * 32; }
            else       { goff = 3u * MATSZ + (c - 7) * CHSTR; bhoff = 1u * BT * HS + (c - 7) * 32; }
        }
        gTab[s] = goff; bhTab[s] = bhoff;
    }
    __syncthreads();

    float creg[3][2][CH];
#pragma unroll
    for (int l = 0; l < 3; ++l)
#pragma unroll
        for (int nt = 0; nt < 2; ++nt)
#pragma unroll
            for (int mt = 0; mt < CH; ++mt) creg[l][nt][mt] = 0.0f;

    const ushort* pk = packed + (size_t)(ct0 * 64) * 8;   // + wave tile offset
    ushort* sl = &stage[wave][0][0];
    ushort* hbflat = &hb[0][0][0];
    const int bhbase = l15 * HS + q * 8;

    // prologue: 2 chunks in flight (20 DMAs); stream never drains
    stage_chunk(pk + gTab[0], sl, lane);
    stage_chunk(pk + gTab[1], sl + SBUF, lane);
    int isl = 2;   // next slot to issue (mod 35)

    for (int t = 0; t < Tlen; ++t) {
        f32x4 acc[2][CH];

        // ---- layer 0 acc init: b0 + W0^T x_t ----
        const float xn0 = bf2f(xTs[t][l15]);
        const float xn1 = bf2f(xTs[t][16 + l15]);
#pragma unroll
        for (int mt = 0; mt < CH; ++mt) {
            const int row = (ct0 + mt) * 16 + q * 4;
            float bb[4], ww[4];
            unpack4(&pbwb[0][row], bb);
            unpack4(&pbwb[3][row], ww);
#pragma unroll
            for (int r = 0; r < 4; ++r) {
                acc[0][mt][r] = fmaf(xn0, ww[r], bb[r]);
                acc[1][mt][r] = fmaf(xn1, ww[r], bb[r]);
            }
        }

        // ---- region A: slots 0..6 (U0 x h0_old) ----
#pragma unroll 1
        for (int s = 0; s < 7; ++s) {
            __builtin_amdgcn_s_waitcnt(WAIT_VM10);
            ushort* buf = sl + ((t + s) & 1) * SBUF;
            s16x8 frag[CH];
#pragma unroll
            for (int mt = 0; mt < CH; ++mt)
                frag[mt] = *(const s16x8*)(buf + mt * 512 + lane * 8);
            const ushort* bp = hbflat + bhTab[s] + bhbase;
            s16x8 bh0 = *(const s16x8*)bp;
            s16x8 bh1 = *(const s16x8*)(bp + 16 * HS);
#pragma unroll
            for (int mt = 0; mt < CH; ++mt) {
                acc[0][mt] = __builtin_amdgcn_mfma_f32_16x16x32_bf16(frag[mt], bh0, acc[0][mt], 0, 0, 0);
                acc[1][mt] = __builtin_amdgcn_mfma_f32_16x16x32_bf16(frag[mt], bh1, acc[1][mt], 0, 0, 0);
            }
            __builtin_amdgcn_s_waitcnt(WAIT_LGKM0);
            stage_chunk(pk + gTab[isl], buf, lane);
            isl = (isl == 34) ? 0 : isl + 1;
        }
        wg_barrier();
        gate_phase(acc, creg[0], hbflat + 0 * BT * HS, lane, ct0);  // h0 in place
        wg_barrier();

        // ---- layer 1 acc init ----
#pragma unroll
        for (int mt = 0; mt < CH; ++mt) {
            const int row = (ct0 + mt) * 16 + q * 4;
            float bb[4];
            unpack4(&pbwb[1][row], bb);
#pragma unroll
            for (int r = 0; r < 4; ++r) { acc[0][mt][r] = bb[r]; acc[1][mt][r] = bb[r]; }
        }
        // ---- region B: slots 7..20 (U1 x h1_old, W1 x h0_new, rotated) ----
#pragma unroll 1
        for (int s = 7; s < 21; ++s) {
            __builtin_amdgcn_s_waitcnt(WAIT_VM10);
            ushort* buf = sl + ((t + s) & 1) * SBUF;
            s16x8 frag[CH];
#pragma unroll
            for (int mt = 0; mt < CH; ++mt)
                frag[mt] = *(const s16x8*)(buf + mt * 512 + lane * 8);
            const ushort* bp = hbflat + bhTab[s] + bhbase;
            s16x8 bh0 = *(const s16x8*)bp;
            s16x8 bh1 = *(const s16x8*)(bp + 16 * HS);
#pragma unroll
            for (int mt = 0; mt < CH; ++mt) {
                acc[0][mt] = __builtin_amdgcn_mfma_f32_16x16x32_bf16(frag[mt], bh0, acc[0][mt], 0, 0, 0);
                acc[1][mt] = __builtin_amdgcn_mfma_f32_16x16x32_bf16(frag[mt], bh1, acc[1][mt], 0, 0, 0);
            }
            __builtin_amdgcn_s_waitcnt(WAIT_LGKM0);
            stage_chunk(pk + gTab[isl], buf, lane);
            isl = (isl == 34) ? 0 : isl + 1;
        }
        wg_barrier();
        gate_phase(acc, creg[1], hbflat + 1 * BT * HS, lane, ct0);  // h1 in place
        wg_barrier();

        // ---- layer 2 acc init ----
#pragma unroll
        for (int mt = 0; mt < CH; ++mt) {
            const int row = (ct0 + mt) * 16 + q * 4;
            float bb[4];
            unpack4(&pbwb[2][row], bb);
#pragma unroll
            for (int r = 0; r < 4; ++r) { acc[0][mt][r] = bb[r]; acc[1][mt][r] = bb[r]; }
        }
        // ---- region C: slots 21..34 (U2 x h2_old, W2 x h1_new, rotated) ----
#pragma unroll 1
        for (int s = 21; s < 35; ++s) {
            __builtin_amdgcn_s_waitcnt(WAIT_VM10);
            ushort* buf = sl + ((t + s) & 1) * SBUF;
            s16x8 frag[CH];
#pragma unroll
            for (int mt = 0; mt < CH; ++mt)
                frag[mt] = *(const s16x8*)(buf + mt * 512 + lane * 8);
            const ushort* bp = hbflat + bhTab[s] + bhbase;
            s16x8 bh0 = *(const s16x8*)bp;
            s16x8 bh1 = *(const s16x8*)(bp + 16 * HS);
#pragma unroll
            for (int mt = 0; mt < CH; ++mt) {
                acc[0][mt] = __builtin_amdgcn_mfma_f32_16x16x32_bf16(frag[mt], bh0, acc[0][mt], 0, 0, 0);
                acc[1][mt] = __builtin_amdgcn_mfma_f32_16x16x32_bf16(frag[mt], bh1, acc[1][mt], 0, 0, 0);
            }
            __builtin_amdgcn_s_waitcnt(WAIT_LGKM0);
            stage_chunk(pk + gTab[isl], buf, lane);   // wraps into next step
            isl = (isl == 34) ? 0 : isl + 1;
        }
        wg_barrier();
        gate_phase(acc, creg[2], hbflat + 2 * BT * HS, lane, ct0);  // h2 in place
        wg_barrier();
    }
    __syncthreads();   // full drain (absorbs wrap DMAs) + h2 visibility

    // ---- dense head: y = tanh(h2 @ Wfc + bfc) ----
    for (int gidx = tid; gidx < BT * 100; gidx += THREADS) {
        int m = gidx / 100;
        int j4 = (gidx % 100) * 4;
        const ushort* h2 = &hb[2][m][0];
        float4 a4 = *(const float4*)(bfc + j4);
        float s0 = a4.x, s1 = a4.y, s2 = a4.z, s3 = a4.w;
        for (int k = 0; k < Hdim; ++k) {
            float hk = bf2f(h2[k]);
            float4 w4 = *(const float4*)(Wfc + (size_t)k * 400 + j4);
            s0 = fmaf(hk, w4.x, s0);
            s1 = fmaf(hk, w4.y, s1);
            s2 = fmaf(hk, w4.z, s2);
            s3 = fmaf(hk, w4.w, s3);
        }
        float4 o4;
        o4.x = tanh_fast(s0); o4.y = tanh_fast(s1);
        o4.z = tanh_fast(s2); o4.w = tanh_fast(s3);
        *(float4*)(out + (size_t)(bbase + m) * 400 + j4) = o4;
    }
}

extern "C" void kernel_launch(void* const* d_in, const int* in_sizes, int n_in,
                              void* d_out, int out_size, void* d_ws, size_t ws_size,
                              hipStream_t stream) {
    const float* x   = (const float*)d_in[0];
    const float* W0  = (const float*)d_in[1];
    const float* U0  = (const float*)d_in[2];
    const float* b0  = (const float*)d_in[3];
    const float* W1  = (const float*)d_in[4];
    const float* U1  = (const float*)d_in[5];
    const float* b1  = (const float*)d_in[6];
    const float* W2  = (const float*)d_in[7];
    const float* U2  = (const float*)d_in[8];
    const float* b2  = (const float*)d_in[9];
    const float* Wfc = (const float*)d_in[10];
    const float* bfc = (const float*)d_in[11];
    float* out = (float*)d_out;
    ushort* packed = (ushort*)d_ws;

    const int B = in_sizes[0] / Tlen;   // 8192
    const int pack_threads = 5 * KB * NT * 64;
    pack_weights<<<(pack_threads + 255) / 256, 256, 0, stream>>>(U0, W1, U1, W2, U2, packed);
    lstm3_mfma<<<B / BT, THREADS, 0, stream>>>(x, W0, b0, b1, b2, Wfc, bfc, packed, out);
}

// Round 12
// 2840.010 us; speedup vs baseline: 1.2945x; 1.2945x over previous
//
#include <hip/hip_runtime.h>

#define Hdim 200
#define NP   800
#define Tlen 100
#define BT   32          // batch rows per WG -> grid = 256 = 1 WG/CU
#define KB   7           // K blocks of 32 (200 -> 224 padded)
#define HS   232         // padded h row stride (ushorts)
#define NT   50          // 800/16 gate-col tiles
#define THREADS 640      // 10 waves x 5 M-tiles each (R9 split: TLP floor at 1 WG/CU)
#define CH   5           // M-tiles per wave
#define CHSTR (NT*64*8)  // ushorts per K-chunk (25600)
#define MATSZ (KB*CHSTR) // 179200 ushorts per packed matrix
#define SBUF  2560       // ushorts per stage buffer (5 tiles x 512)

// s_waitcnt immediates: vm[3:0]|exp[6:4]|lgkm[11:8]|vm[5:4]@[15:14]
#define WAIT_VM5   0x0F75   // vmcnt(5): chunk c landed, chunk c+1 in flight
#define WAIT_LGKM0 0xC07F   // lgkmcnt(0)

typedef float f32x4 __attribute__((ext_vector_type(4)));
typedef short s16x8 __attribute__((ext_vector_type(8)));

__device__ __forceinline__ ushort f2bf(float f) {
    unsigned u = __float_as_uint(f);
    return (ushort)((u + 0x7fffu + ((u >> 16) & 1u)) >> 16);   // RTNE
}
__device__ __forceinline__ float bf2f(ushort s) {
    return __uint_as_float(((unsigned)s) << 16);
}
__device__ __forceinline__ float sigmoid_fast(float v) {
    return 1.0f / (1.0f + __expf(-v));
}
__device__ __forceinline__ float tanh_fast(float v) {
    return 2.0f / (1.0f + __expf(-2.0f * v)) - 1.0f;
}
// WG barrier WITHOUT vmcnt drain (weight DMAs stay in flight across it).
__device__ __forceinline__ void wg_barrier() {
    asm volatile("" ::: "memory");
    __builtin_amdgcn_s_waitcnt(WAIT_LGKM0);
    __builtin_amdgcn_s_barrier();
    asm volatile("" ::: "memory");
}

// ---- pack 5 recurrent matrices [200][800] fp32 -> bf16 fragment layout ----
// order in d_ws: [U0, W1, U1, W2, U2]
__global__ void pack_weights(const float* __restrict__ U0, const float* __restrict__ W1,
                             const float* __restrict__ U1, const float* __restrict__ W2,
                             const float* __restrict__ U2, ushort* __restrict__ dst) {
    int idx = blockIdx.x * blockDim.x + threadIdx.x;
    if (idx >= 5 * KB * NT * 64) return;
    int lane = idx & 63; int rest = idx >> 6;
    int nt = rest % NT; rest /= NT;
    int kb = rest % KB; int mi = rest / KB;
    const float* src = (mi == 0) ? U0 : (mi == 1) ? W1 : (mi == 2) ? U1 : (mi == 3) ? W2 : U2;
    int np = nt * 16 + (lane & 15);
    int ncol = (np & 3) * Hdim + (np >> 2);          // gate*200 + unit
    int k0 = kb * 32 + (lane >> 4) * 8;
    ushort v[8];
#pragma unroll
    for (int j = 0; j < 8; ++j) {
        int k = k0 + j;
        v[j] = (k < Hdim) ? f2bf(src[k * NP + ncol]) : (ushort)0;
    }
    uint4 o;
    o.x = (unsigned)v[0] | ((unsigned)v[1] << 16);
    o.y = (unsigned)v[2] | ((unsigned)v[3] << 16);
    o.z = (unsigned)v[4] | ((unsigned)v[5] << 16);
    o.w = (unsigned)v[6] | ((unsigned)v[7] << 16);
    ((uint4*)dst)[idx] = o;
}

// 5 async DMAs: one K-chunk's 5 fragment tiles -> wave-private LDS buffer.
// (imm offset must be a front-end constant -> keep per-tile pointer math)
__device__ __forceinline__ void stage_chunk(const ushort* gp, ushort* dstbuf, int lane) {
#pragma unroll
    for (int mt = 0; mt < CH; ++mt) {
        __builtin_amdgcn_global_load_lds(
            (const __attribute__((address_space(1))) void*)(gp + (size_t)mt * 512 + lane * 8),
            (__attribute__((address_space(3))) void*)(dstbuf + mt * 512),
            16, 0, 0);
    }
}

__device__ __forceinline__ void unpack4(const ushort* p, float (&o)[4]) {
    uint2 u = *(const uint2*)p;
    o[0] = bf2f((ushort)(u.x));  o[1] = bf2f((ushort)(u.x >> 16));
    o[2] = bf2f((ushort)(u.y));  o[3] = bf2f((ushort)(u.y >> 16));
}

// One 7-chunk region [S0,S1): consume slot s (vmcnt(5)), 10 MFMAs, then
// refill the buffer with slot isl's chunk (never-drain pipeline).
template<int S0, int S1>
__device__ __forceinline__ void do_region(f32x4 (&acc)[2][CH],
                                          const ushort* __restrict__ pk, ushort* sl,
                                          const uint* __restrict__ gTab,
                                          const uint* __restrict__ bhTab,
                                          const ushort* __restrict__ hbflat,
                                          int bhbase, int lane, int t, int& isl) {
#pragma unroll 1
    for (int s = S0; s < S1; ++s) {
        __builtin_amdgcn_s_waitcnt(WAIT_VM5);
        ushort* buf = sl + ((t + s) & 1) * SBUF;
        s16x8 frag[CH];
#pragma unroll
        for (int mt = 0; mt < CH; ++mt)
            frag[mt] = *(const s16x8*)(buf + mt * 512 + lane * 8);
        const ushort* bp = hbflat + bhTab[s] + bhbase;
        s16x8 bh0 = *(const s16x8*)bp;
        s16x8 bh1 = *(const s16x8*)(bp + 16 * HS);
#pragma unroll
        for (int mt = 0; mt < CH; ++mt) {
            acc[0][mt] = __builtin_amdgcn_mfma_f32_16x16x32_bf16(frag[mt], bh0, acc[0][mt], 0, 0, 0);
            acc[1][mt] = __builtin_amdgcn_mfma_f32_16x16x32_bf16(frag[mt], bh1, acc[1][mt], 0, 0, 0);
        }
        __builtin_amdgcn_s_waitcnt(WAIT_LGKM0);   // frag reads retired before overwrite
        stage_chunk(pk + gTab[isl], buf, lane);
        isl = (isl == 34) ? 0 : isl + 1;
    }
}

// lane-local cell update: acc[nt][mt] regs r=0..3 = gates i,f,g,o of
// unit u=(ct0+mt)*4+q, batch n=nt*16+l15.
__device__ __forceinline__ void gate_phase(f32x4 (&acc)[2][CH],
                                           float (&creg)[2][CH],
                                           ushort* __restrict__ hbl,
                                           int lane, int ct0) {
    const int l15 = lane & 15, q = lane >> 4;
#pragma unroll
    for (int nt = 0; nt < 2; ++nt) {
#pragma unroll
        for (int mt = 0; mt < CH; ++mt) {
            const int u = (ct0 + mt) * 4 + q;
            const int n = nt * 16 + l15;
            f32x4 z = acc[nt][mt];
            float iv = sigmoid_fast(z[0]);
            float fv = sigmoid_fast(z[1]);
            float gv = tanh_fast(z[2]);
            float ov = sigmoid_fast(z[3]);
            float c = fv * creg[nt][mt] + iv * gv;
            creg[nt][mt] = c;
            hbl[n * HS + u] = f2bf(ov * tanh_fast(c));
        }
    }
}

__global__ void __launch_bounds__(THREADS)
lstm3_mfma(const float* __restrict__ x,
           const float* __restrict__ W0, const float* __restrict__ b0,
           const float* __restrict__ b1, const float* __restrict__ b2,
           const float* __restrict__ Wfc, const float* __restrict__ bfc,
           const ushort* __restrict__ packed,
           float* __restrict__ out) {
    __shared__ ushort hb[3][BT][HS];        // h state, bf16, in place (44.5 KB)
    __shared__ ushort stage[10][2][SBUF];   // 2-deep wave-private staging (100 KB)
    __shared__ ushort pbwb[4][NP];          // permuted b0,b1,b2,W0 as bf16 (6.4 KB)
    __shared__ ushort xTs[Tlen][BT];        // x transposed, bf16 (6.4 KB)
    __shared__ uint   gTab[35];             // rotated weight-chunk offsets
    __shared__ uint   bhTab[35];            // matching h-operand offsets

    const int tid = threadIdx.x;
    const int wave = tid >> 6, lane = tid & 63;
    const int l15 = lane & 15, q = lane >> 4;
    const int ct0 = wave * CH;
    const int bx = blockIdx.x;
    const int bbase = bx * BT;

    for (int i = tid; i < 3 * BT * HS; i += THREADS) ((ushort*)hb)[i] = 0;
    for (int i = tid; i < NP; i += THREADS) {
        int nc = (i & 3) * Hdim + (i >> 2);   // permuted col -> src col
        pbwb[0][i] = f2bf(b0[nc]); pbwb[1][i] = f2bf(b1[nc]);
        pbwb[2][i] = f2bf(b2[nc]); pbwb[3][i] = f2bf(W0[nc]);
    }
    for (int i = tid; i < BT * Tlen; i += THREADS) {
        int m = i / Tlen, tt = i % Tlen;
        xTs[tt][m] = f2bf(x[(size_t)(bbase + m) * Tlen + tt]);
    }
    // slot tables. Schedule per step: U0 |b1| g0,U1 |b2| W1,g1,U2 |b3| W2,g2
    // per-WG rotation of chunk order inside each 7-chunk region (L2 decorrelation)
    if (tid < 35) {
        int s = tid; int r = s % 7; int c = (r + bx) % 7;
        uint goff, bhoff;
        if (s < 7)       { goff = 0u * MATSZ + c * CHSTR; bhoff = 0u * BT * HS + c * 32; }  // U0 x h0
        else if (s < 14) { goff = 2u * MATSZ + c * CHSTR; bhoff = 1u * BT * HS + c * 32; }  // U1 x h1_old
        else if (s < 21) { goff = 1u * MATSZ + c * CHSTR; bhoff = 0u * BT * HS + c * 32; }  // W1 x h0_new
        else if (s < 28) { goff = 4u * MATSZ + c * CHSTR; bhoff = 2u * BT * HS + c * 32; }  // U2 x h2_old
        else             { goff = 3u * MATSZ + c * CHSTR; bhoff = 1u * BT * HS + c * 32; }  // W2 x h1_new
        gTab[s] = goff; bhTab[s] = bhoff;
    }
    __syncthreads();

    float creg[3][2][CH];
#pragma unroll
    for (int l = 0; l < 3; ++l)
#pragma unroll
        for (int nt = 0; nt < 2; ++nt)
#pragma unroll
            for (int mt = 0; mt < CH; ++mt) creg[l][nt][mt] = 0.0f;

    const ushort* pk = packed + (size_t)(ct0 * 64) * 8;   // + wave tile offset
    ushort* sl = &stage[wave][0][0];
    ushort* hbflat = &hb[0][0][0];
    const int bhbase = l15 * HS + q * 8;

    // prologue: 2 chunks in flight (10 DMAs); stream never drains
    stage_chunk(pk + gTab[0], sl, lane);
    stage_chunk(pk + gTab[1], sl + SBUF, lane);
    int isl = 2;   // next slot to issue (mod 35)

    for (int t = 0; t < Tlen; ++t) {
        f32x4 acc[2][CH];

        // ---- layer 0 acc init: b0 + W0^T x_t ----
        const float xn0 = bf2f(xTs[t][l15]);
        const float xn1 = bf2f(xTs[t][16 + l15]);
#pragma unroll
        for (int mt = 0; mt < CH; ++mt) {
            const int row = (ct0 + mt) * 16 + q * 4;
            float bb[4], ww[4];
            unpack4(&pbwb[0][row], bb);
            unpack4(&pbwb[3][row], ww);
#pragma unroll
            for (int r = 0; r < 4; ++r) {
                acc[0][mt][r] = fmaf(xn0, ww[r], bb[r]);
                acc[1][mt][r] = fmaf(xn1, ww[r], bb[r]);
            }
        }
        // U0 x h0_old
        do_region<0, 7>(acc, pk, sl, gTab, bhTab, hbflat, bhbase, lane, t, isl);
        wg_barrier();                                  // b1: h0_old reads done
        gate_phase(acc, creg[0], hbflat + 0 * BT * HS, lane, ct0);   // write h0

        // ---- layer 1 acc init, then U1 x h1_old (overlaps other waves' gate0) ----
#pragma unroll
        for (int mt = 0; mt < CH; ++mt) {
            const int row = (ct0 + mt) * 16 + q * 4;
            float bb[4];
            unpack4(&pbwb[1][row], bb);
#pragma unroll
            for (int r = 0; r < 4; ++r) { acc[0][mt][r] = bb[r]; acc[1][mt][r] = bb[r]; }
        }
        do_region<7, 14>(acc, pk, sl, gTab, bhTab, hbflat, bhbase, lane, t, isl);
        wg_barrier();                                  // b2: h0 writes visible; h1_old reads done
        // W1 x h0_new, then gate1 (WAR on h1 separated by b2)
        do_region<14, 21>(acc, pk, sl, gTab, bhTab, hbflat, bhbase, lane, t, isl);
        gate_phase(acc, creg[1], hbflat + 1 * BT * HS, lane, ct0);   // write h1

        // ---- layer 2 acc init, then U2 x h2_old ----
#pragma unroll
        for (int mt = 0; mt < CH; ++mt) {
            const int row = (ct0 + mt) * 16 + q * 4;
            float bb[4];
            unpack4(&pbwb[2][row], bb);
#pragma unroll
            for (int r = 0; r < 4; ++r) { acc[0][mt][r] = bb[r]; acc[1][mt][r] = bb[r]; }
        }
        do_region<21, 28>(acc, pk, sl, gTab, bhTab, hbflat, bhbase, lane, t, isl);
        wg_barrier();                                  // b3: h1 writes visible; h2_old reads done
        // W2 x h1_new, then gate2 (WAR on h2 separated by b3)
        do_region<28, 35>(acc, pk, sl, gTab, bhTab, hbflat, bhbase, lane, t, isl);
        gate_phase(acc, creg[2], hbflat + 2 * BT * HS, lane, ct0);   // write h2
        // next step: U0 reads h0 (visible since b2/b3); h2 readers sit behind b1',b2'
    }
    __syncthreads();   // full drain (absorbs wrap DMAs) + h2 visibility

    // ---- dense head: y = tanh(h2 @ Wfc + bfc) ----
    for (int gidx = tid; gidx < BT * 100; gidx += THREADS) {
        int m = gidx / 100;
        int j4 = (gidx % 100) * 4;
        const ushort* h2 = &hb[2][m][0];
        float4 a4 = *(const float4*)(bfc + j4);
        float s0 = a4.x, s1 = a4.y, s2 = a4.z, s3 = a4.w;
        for (int k = 0; k < Hdim; ++k) {
            float hk = bf2f(h2[k]);
            float4 w4 = *(const float4*)(Wfc + (size_t)k * 400 + j4);
            s0 = fmaf(hk, w4.x, s0);
            s1 = fmaf(hk, w4.y, s1);
            s2 = fmaf(hk, w4.z, s2);
            s3 = fmaf(hk, w4.w, s3);
        }
        float4 o4;
        o4.x = tanh_fast(s0); o4.y = tanh_fast(s1);
        o4.z = tanh_fast(s2); o4.w = tanh_fast(s3);
        *(float4*)(out + (size_t)(bbase + m) * 400 + j4) = o4;
    }
}

extern "C" void kernel_launch(void* const* d_in, const int* in_sizes, int n_in,
                              void* d_out, int out_size, void* d_ws, size_t ws_size,
                              hipStream_t stream) {
    const float* x   = (const float*)d_in[0];
    const float* W0  = (const float*)d_in[1];
    const float* U0  = (const float*)d_in[2];
    const float* b0  = (const float*)d_in[3];
    const float* W1  = (const float*)d_in[4];
    const float* U1  = (const float*)d_in[5];
    const float* b1  = (const float*)d_in[6];
    const float* W2  = (const float*)d_in[7];
    const float* U2  = (const float*)d_in[8];
    const float* b2  = (const float*)d_in[9];
    const float* Wfc = (const float*)d_in[10];
    const float* bfc = (const float*)d_in[11];
    float* out = (float*)d_out;
    ushort* packed = (ushort*)d_ws;

    const int B = in_sizes[0] / Tlen;   // 8192
    const int pack_threads = 5 * KB * NT * 64;
    pack_weights<<<(pack_threads + 255) / 256, 256, 0, stream>>>(U0, W1, U1, W2, U2, packed);
    lstm3_mfma<<<B / BT, THREADS, 0, stream>>>(x, W0, b0, b1, b2, Wfc, bfc, packed, out);
}